// Round 1
// 1779.124 us; speedup vs baseline: 6.1046x; 6.1046x over previous
//
#include <hip/hip_runtime.h>
#include <hip/hip_bf16.h>

// GPT_90202903150925 — 4-layer GPT forward on gfx950.
// Round 3: MFMA flash attention.
//   - old wave-per-row VALU attention (2615 us/layer, MfmaUtil=0) replaced by
//     16-query-per-wave flash attention using mfma_f32_16x16x32_bf16
//   - QK^T computed swapped (S^T = mfma(K,Q)) so softmax is per-lane + 2 shfl_xor
//   - V^T produced directly by the QKV GEMM epilogue (MODE 4) into a buffer
//     aliasing mlpbuf (unused during attention) -> PV B-operand is contiguous
//   - P quantized to bf16 before row-sum so denominator matches numerator

typedef __hip_bfloat16 bf16;
typedef __attribute__((ext_vector_type(8))) short short8;
typedef __attribute__((ext_vector_type(4))) float floatx4;

#define Bsz 2
#define Lseq 2048
#define Dmod 512
#define NHn 8
#define NLn 4
#define DMn 2048
#define Vn 32000
#define HDn 64
#define Mrows 4096  // B*L

// ------------- transpose+cast: src_f32[R][C] -> dst_bf16[C][R] -------------
__global__ void transpose_kernel(const float* __restrict__ src, bf16* __restrict__ dst,
                                 int R, int C) {
    __shared__ float tile[32][33];
    int c0 = blockIdx.x * 32, r0 = blockIdx.y * 32;
    int tx = threadIdx.x, ty = threadIdx.y;  // block (32,8)
    #pragma unroll
    for (int i = 0; i < 32; i += 8)
        tile[ty + i][tx] = src[(long)(r0 + ty + i) * C + (c0 + tx)];
    __syncthreads();
    #pragma unroll
    for (int i = 0; i < 32; i += 8)
        dst[(long)(c0 + ty + i) * R + (r0 + tx)] = (bf16)tile[tx][ty + i];
}

// ---------------- embedding: h = tok_emb[x] + pos_emb (all f32) ----------------
__global__ __launch_bounds__(256) void embed_kernel(const int* __restrict__ x,
                                                    const float* __restrict__ tok,
                                                    const float* __restrict__ pos,
                                                    float* __restrict__ h) {
    int row = blockIdx.x;            // b*L + l
    int l = row & (Lseq - 1);
    int t = x[row];
    int d = threadIdx.x;
    #pragma unroll
    for (int i = 0; i < Dmod; i += 256) {
        int c = d + i;
        h[(long)row * Dmod + c] = tok[(long)t * Dmod + c] + pos[(long)l * Dmod + c];
    }
}

// ---------------- layernorm: out_bf16 = LN(h_f32)*g + b (g,b f32) ----------------
__global__ __launch_bounds__(256) void ln_kernel(const float* __restrict__ h,
                                                 const float* __restrict__ g,
                                                 const float* __restrict__ b,
                                                 bf16* __restrict__ out) {
    int wave = threadIdx.x >> 6, lane = threadIdx.x & 63;
    int row = blockIdx.x * 4 + wave;
    const float* hr = h + (long)row * Dmod;
    float v[8];
    float s = 0.f;
    #pragma unroll
    for (int i = 0; i < 8; i++) { v[i] = hr[i * 64 + lane]; s += v[i]; }
    #pragma unroll
    for (int o = 32; o > 0; o >>= 1) s += __shfl_xor(s, o, 64);
    float mu = s * (1.0f / Dmod);
    float sq = 0.f;
    #pragma unroll
    for (int i = 0; i < 8; i++) { float d0 = v[i] - mu; sq += d0 * d0; }
    #pragma unroll
    for (int o = 32; o > 0; o >>= 1) sq += __shfl_xor(sq, o, 64);
    float rstd = rsqrtf(sq * (1.0f / Dmod) + 1e-5f);
    #pragma unroll
    for (int i = 0; i < 8; i++) {
        int c = i * 64 + lane;
        out[(long)row * Dmod + c] = (bf16)((v[i] - mu) * rstd * g[c] + b[c]);
    }
}

// ---------------- GEMM: C[M,N] = A[M,K] @ B[K,N] (+bias f32), B given as BT[N,K]
// MODE 0: store bf16; MODE 1: gelu(exact)->bf16; MODE 2: h_f32 += C; MODE 3: store f32
// MODE 4: qkv special — cols [0,1024) -> outb (Q,K); cols [1024,1536) (=V) -> vtb
//         transposed per head: vtb[(b*8+h)*64 + d][k]  (k contiguous, stride Lseq)
template <int MODE>
__global__ __launch_bounds__(256) void gemm_kernel(const bf16* __restrict__ A,
                                                   const bf16* __restrict__ BT,
                                                   const float* __restrict__ bias,
                                                   float* __restrict__ h,
                                                   bf16* __restrict__ outb,
                                                   float* __restrict__ outf,
                                                   bf16* __restrict__ vtb,
                                                   int N, int K) {
    __shared__ __align__(16) short As[128][40];  // +8 pad: 2-way banks only (free)
    __shared__ __align__(16) short Bs[128][40];
    const int tid = threadIdx.x;
    const int wave = tid >> 6, lane = tid & 63;
    const int bm = blockIdx.y, bn = blockIdx.x;
    const int wm = (wave >> 1) * 64, wn = (wave & 1) * 64;
    const int quad = lane >> 4, l16 = lane & 15;

    floatx4 acc[4][4] = {};

    const int r0 = tid >> 2;          // 0..63
    const int kc = (tid & 3) * 8;     // 0,8,16,24
    const long arow0 = (long)(bm * 128 + r0) * K;
    const long arow1 = (long)(bm * 128 + 64 + r0) * K;
    const long brow0 = (long)(bn * 128 + r0) * K;
    const long brow1 = (long)(bn * 128 + 64 + r0) * K;

    for (int k0 = 0; k0 < K; k0 += 32) {
        __syncthreads();
        *(float4*)&As[r0][kc]      = *(const float4*)(A + arow0 + k0 + kc);
        *(float4*)&As[64 + r0][kc] = *(const float4*)(A + arow1 + k0 + kc);
        *(float4*)&Bs[r0][kc]      = *(const float4*)(BT + brow0 + k0 + kc);
        *(float4*)&Bs[64 + r0][kc] = *(const float4*)(BT + brow1 + k0 + kc);
        __syncthreads();
        short8 af[4], bfr[4];
        #pragma unroll
        for (int t = 0; t < 4; t++) {
            af[t]  = *(const short8*)&As[wm + t * 16 + l16][quad * 8];
            bfr[t] = *(const short8*)&Bs[wn + t * 16 + l16][quad * 8];
        }
        #pragma unroll
        for (int mt = 0; mt < 4; mt++)
            #pragma unroll
            for (int nt = 0; nt < 4; nt++)
                acc[mt][nt] = __builtin_amdgcn_mfma_f32_16x16x32_bf16(af[mt], bfr[nt], acc[mt][nt], 0, 0, 0);
    }

    #pragma unroll
    for (int mt = 0; mt < 4; mt++) {
        int row = bm * 128 + wm + mt * 16 + quad * 4;
        #pragma unroll
        for (int nt = 0; nt < 4; nt++) {
            int col = bn * 128 + wn + nt * 16 + l16;
            float bv = bias ? bias[col] : 0.0f;
            #pragma unroll
            for (int r = 0; r < 4; r++) {
                float c = acc[mt][nt][r] + bv;
                long off = (long)(row + r) * N + col;
                if (MODE == 0) {
                    outb[off] = (bf16)c;
                } else if (MODE == 1) {
                    float gl = 0.5f * c * (1.0f + erff(c * 0.70710678118f));
                    outb[off] = (bf16)gl;
                } else if (MODE == 2) {
                    h[off] += c;
                } else if (MODE == 3) {
                    outf[off] = c;
                } else {  // MODE 4: QKV with V transposed per head
                    if (col < 2 * Dmod) {
                        outb[off] = (bf16)c;
                    } else {
                        int d  = col - 2 * Dmod;        // 0..511 (= h*64 + dd)
                        int b_ = (row + r) >> 11;       // batch
                        int k  = (row + r) & (Lseq - 1);
                        vtb[(long)(b_ * 512 + d) * Lseq + k] = (bf16)c;
                    }
                }
            }
        }
    }
}

// ---------------- MFMA flash attention ----------------
// One wave = one 16-query tile of one (b,h). Iterates 32-key blocks.
// S^T = mfma(K_frag, Q_frag): C col = query = lane&15, row = key = quad*4+r.
// Online softmax per query is in-register + shfl_xor(16/32) across quads.
// PV: O += P·V via mfma(P_frag, VT_frag); P_frag built from S^T via 16 shfls.
__global__ __launch_bounds__(256) void attn_mfma_kernel(const bf16* __restrict__ qkv,
                                                        const bf16* __restrict__ vt,
                                                        bf16* __restrict__ o_out) {
    const int tid  = threadIdx.x;
    const int wave = tid >> 6, lane = tid & 63;
    const int l16  = lane & 15, quad = lane >> 4;
    const int bh = blockIdx.x & 15;            // 4 waves of a block share (b,h)
    const int jg = blockIdx.x >> 4;            // 0..31
    const int qb = 127 - (jg * 4 + wave);      // heavy q-tiles dispatched first
    const int b = bh >> 3, h = bh & 7;
    const int q0 = qb * 16;

    const bf16* qbase = qkv + (long)(b * Lseq + q0 + l16) * 1536 + h * 64;
    const bf16* kbase = qkv + (long)b * Lseq * 1536 + Dmod + h * 64;
    const bf16* vbase = vt + (long)(bh * 64 + l16) * Lseq;

    const short8 qf0 = *(const short8*)(qbase + quad * 8);        // Q[q=l16][d 0..31]
    const short8 qf1 = *(const short8*)(qbase + 32 + quad * 8);   // Q[q=l16][d 32..63]

    floatx4 o_acc[4] = {};        // o_acc[nt][r] = O[q=quad*4+r][d=nt*16+l16]
    float m = -1e30f, lsum = 0.f;
    const int qg = q0 + l16;      // this lane's query (softmax domain)
    const float scale = 0.125f;   // 1/sqrt(64)

    for (int k0 = 0; k0 < q0 + 16; k0 += 32) {
        // ---- S^T for keys [k0, k0+32) : two 16x16 tiles ----
        const bf16* krow0 = kbase + (long)(k0 + l16) * 1536;
        const bf16* krow1 = kbase + (long)(k0 + 16 + l16) * 1536;
        floatx4 s0 = {}, s1 = {};
        {
            short8 kf;
            kf = *(const short8*)(krow0 + quad * 8);
            s0 = __builtin_amdgcn_mfma_f32_16x16x32_bf16(kf, qf0, s0, 0, 0, 0);
            kf = *(const short8*)(krow0 + 32 + quad * 8);
            s0 = __builtin_amdgcn_mfma_f32_16x16x32_bf16(kf, qf1, s0, 0, 0, 0);
            kf = *(const short8*)(krow1 + quad * 8);
            s1 = __builtin_amdgcn_mfma_f32_16x16x32_bf16(kf, qf0, s1, 0, 0, 0);
            kf = *(const short8*)(krow1 + 32 + quad * 8);
            s1 = __builtin_amdgcn_mfma_f32_16x16x32_bf16(kf, qf1, s1, 0, 0, 0);
        }

        // ---- scale + causal mask (key idx: tile0 = k0+quad*4+r, tile1 = +16) ----
        float t0[4], t1[4];
        #pragma unroll
        for (int r = 0; r < 4; r++) {
            int ka = k0 + quad * 4 + r;
            t0[r] = (ka <= qg)      ? s0[r] * scale : -1e30f;
            t1[r] = (ka + 16 <= qg) ? s1[r] * scale : -1e30f;
        }

        // ---- online softmax per query (= l16 column) ----
        float pm = fmaxf(fmaxf(fmaxf(t0[0], t0[1]), fmaxf(t0[2], t0[3])),
                         fmaxf(fmaxf(t1[0], t1[1]), fmaxf(t1[2], t1[3])));
        pm = fmaxf(pm, __shfl_xor(pm, 16, 64));
        pm = fmaxf(pm, __shfl_xor(pm, 32, 64));
        float mnew  = fmaxf(m, pm);
        float alpha = __expf(m - mnew);
        float p0[4], p1[4], es = 0.f;
        #pragma unroll
        for (int r = 0; r < 4; r++) {
            // quantize P to bf16 BEFORE summing so denominator matches PV numerator
            bf16 qa = (bf16)__expf(t0[r] - mnew);
            bf16 qb2 = (bf16)__expf(t1[r] - mnew);
            p0[r] = (float)qa;
            p1[r] = (float)qb2;
            es += p0[r] + p1[r];
        }
        es += __shfl_xor(es, 16, 64);
        es += __shfl_xor(es, 32, 64);
        lsum = lsum * alpha + es;
        m = mnew;

        // ---- rescale O (its rows are queries quad*4+r, need their alpha) ----
        #pragma unroll
        for (int r = 0; r < 4; r++) {
            float aq = __shfl(alpha, quad * 4 + r, 64);
            o_acc[0][r] *= aq; o_acc[1][r] *= aq;
            o_acc[2][r] *= aq; o_acc[3][r] *= aq;
        }

        // ---- build P A-fragment: lane needs P[q=l16][k0 + quad*8 + j], j=0..7 ----
        // source: P^T[k][q=l16] lives at lane (l16, srcquad=(k&15)>>2), tile=k>>4
        const int sl0 = l16 | (((quad * 2) & 3) << 4);
        const int sl1 = l16 | (((quad * 2 + 1) & 3) << 4);
        short8 pf;
        #pragma unroll
        for (int r = 0; r < 4; r++) {
            float a0 = __shfl(p0[r], sl0, 64);
            float a1 = __shfl(p1[r], sl0, 64);
            float va = (quad < 2) ? a0 : a1;     // tile = quad>>1
            float b0 = __shfl(p0[r], sl1, 64);
            float b1 = __shfl(p1[r], sl1, 64);
            float vb = (quad < 2) ? b0 : b1;
            bf16 ta = (bf16)va;                  // exact: already bf16-quantized
            bf16 tb = (bf16)vb;
            pf[r]     = __builtin_bit_cast(short, ta);
            pf[4 + r] = __builtin_bit_cast(short, tb);
        }

        // ---- PV: O[q][d] += P·V, B-frag = VT[d=nt*16+l16][k0+quad*8+j] ----
        const bf16* vrow = vbase + k0 + quad * 8;
        #pragma unroll
        for (int nt = 0; nt < 4; nt++) {
            short8 vf = *(const short8*)(vrow + (long)nt * 16 * Lseq);
            o_acc[nt] = __builtin_amdgcn_mfma_f32_16x16x32_bf16(pf, vf, o_acc[nt], 0, 0, 0);
        }
    }

    // ---- epilogue: normalize rows by their lsum and store ----
    #pragma unroll
    for (int r = 0; r < 4; r++) {
        float lq  = __shfl(lsum, quad * 4 + r, 64);
        float inv = 1.0f / lq;
        int row = b * Lseq + q0 + quad * 4 + r;
        #pragma unroll
        for (int nt = 0; nt < 4; nt++)
            o_out[(long)row * Dmod + h * 64 + nt * 16 + l16] = (bf16)(o_acc[nt][r] * inv);
    }
}

// ---------------- host launch ----------------
extern "C" void kernel_launch(void* const* d_in, const int* in_sizes, int n_in,
                              void* d_out, int out_size, void* d_ws, size_t ws_size,
                              hipStream_t stream) {
    const int*   x      = (const int*)d_in[0];
    const float* tok    = (const float*)d_in[1];
    const float* pos    = (const float*)d_in[2];
    const float* ln1_g  = (const float*)d_in[3];
    const float* ln1_b  = (const float*)d_in[4];
    const float* qkv_w  = (const float*)d_in[5];
    const float* qkv_b  = (const float*)d_in[6];
    const float* out_w  = (const float*)d_in[7];
    const float* out_b  = (const float*)d_in[8];
    const float* ln2_g  = (const float*)d_in[9];
    const float* ln2_b  = (const float*)d_in[10];
    const float* w1     = (const float*)d_in[11];
    const float* b1     = (const float*)d_in[12];
    const float* w2     = (const float*)d_in[13];
    const float* b2     = (const float*)d_in[14];
    const float* lnf_g  = (const float*)d_in[15];
    const float* lnf_b  = (const float*)d_in[16];
    const float* head_w = (const float*)d_in[17];
    float* out = (float*)d_out;

    char* w = (char*)d_ws;
    float* h      = (float*)(w + 0);              // 4096x512 f32    =  8,388,608
    bf16*  lnbuf  = (bf16*)(w + 8388608);         // 4096x512 bf16   =  4,194,304
    bf16*  qkvbuf = (bf16*)(w + 12582912);        // 4096x1536 bf16  = 12,582,912
    bf16*  attn_o = (bf16*)(w + 25165824);        // 4096x512 bf16   =  4,194,304
    bf16*  mlpbuf = (bf16*)(w + 29360128);        // 4096x2048 bf16  = 16,777,216
    bf16*  vT     = mlpbuf;                       // VT[1024][2048] bf16 = 4 MB,
                                                  // aliases mlpbuf (free during attn)
    bf16*  qkvT   = (bf16*)(w + 46137344);        // 4x1536x512      =  6,291,456
    bf16*  outT   = (bf16*)(w + 52428800);        // 4x512x512       =  2,097,152
    bf16*  w1T    = (bf16*)(w + 54525952);        // 4x2048x512      =  8,388,608
    bf16*  w2T    = (bf16*)(w + 62914560);        // 4x512x2048      =  8,388,608
    bf16*  headT  = (bf16*)(w + 71303168);        // 32000x512       = 32,768,000
    // total ws need: 104,071,168 bytes

    dim3 tb(32, 8);
    for (int l = 0; l < NLn; l++) {
        transpose_kernel<<<dim3(3 * Dmod / 32, Dmod / 32), tb, 0, stream>>>(
            qkv_w + (long)l * Dmod * 3 * Dmod, qkvT + (long)l * 3 * Dmod * Dmod, Dmod, 3 * Dmod);
        transpose_kernel<<<dim3(Dmod / 32, Dmod / 32), tb, 0, stream>>>(
            out_w + (long)l * Dmod * Dmod, outT + (long)l * Dmod * Dmod, Dmod, Dmod);
        transpose_kernel<<<dim3(DMn / 32, Dmod / 32), tb, 0, stream>>>(
            w1 + (long)l * Dmod * DMn, w1T + (long)l * DMn * Dmod, Dmod, DMn);
        transpose_kernel<<<dim3(Dmod / 32, DMn / 32), tb, 0, stream>>>(
            w2 + (long)l * DMn * Dmod, w2T + (long)l * Dmod * DMn, DMn, Dmod);
    }
    transpose_kernel<<<dim3(Vn / 32, Dmod / 32), tb, 0, stream>>>(head_w, headT, Dmod, Vn);

    embed_kernel<<<Mrows, 256, 0, stream>>>(x, tok, pos, h);

    for (int l = 0; l < NLn; l++) {
        ln_kernel<<<Mrows / 4, 256, 0, stream>>>(h, ln1_g + l * Dmod, ln1_b + l * Dmod, lnbuf);
        gemm_kernel<4><<<dim3(3 * Dmod / 128, Mrows / 128), 256, 0, stream>>>(
            lnbuf, qkvT + (long)l * 3 * Dmod * Dmod, qkv_b + l * 3 * Dmod, nullptr, qkvbuf,
            nullptr, vT, 3 * Dmod, Dmod);
        attn_mfma_kernel<<<512, 256, 0, stream>>>(qkvbuf, vT, attn_o);
        gemm_kernel<2><<<dim3(Dmod / 128, Mrows / 128), 256, 0, stream>>>(
            attn_o, outT + (long)l * Dmod * Dmod, out_b + l * Dmod, h, nullptr, nullptr,
            nullptr, Dmod, Dmod);
        ln_kernel<<<Mrows / 4, 256, 0, stream>>>(h, ln2_g + l * Dmod, ln2_b + l * Dmod, lnbuf);
        gemm_kernel<1><<<dim3(DMn / 128, Mrows / 128), 256, 0, stream>>>(
            lnbuf, w1T + (long)l * DMn * Dmod, b1 + l * DMn, nullptr, mlpbuf, nullptr,
            nullptr, DMn, Dmod);
        gemm_kernel<2><<<dim3(Dmod / 128, Mrows / 128), 256, 0, stream>>>(
            mlpbuf, w2T + (long)l * Dmod * DMn, b2 + l * Dmod, h, nullptr, nullptr,
            nullptr, Dmod, DMn);
    }
    ln_kernel<<<Mrows / 4, 256, 0, stream>>>(h, lnf_g, lnf_b, lnbuf);
    gemm_kernel<3><<<dim3(Vn / 128, Mrows / 128), 256, 0, stream>>>(
        lnbuf, headT, nullptr, nullptr, nullptr, out, nullptr, Vn, Dmod);
}

// Round 2
// 1642.417 us; speedup vs baseline: 6.6127x; 1.0832x over previous
//
#include <hip/hip_runtime.h>
#include <hip/hip_bf16.h>

// GPT_90202903150925 — 4-layer GPT forward on gfx950.
// Round 4:
//   - GEMM upgraded to m97-style staging: __builtin_amdgcn_global_load_lds
//     width=16, linear LDS (proven +69% on this exact tile geometry)
//   - BM=64 tile variant for small-N GEMMs (out-proj/MLP2: 128->256 blocks,
//     QKV: 384->768 blocks) to fill all 256 CUs
//   - attention: 64-key inner step (half the softmax serial chains) +
//     defer-max (skip rescale when __all(pm<=m), exact)

typedef __hip_bfloat16 bf16;
typedef __attribute__((ext_vector_type(8))) short short8;
typedef __attribute__((ext_vector_type(4))) float floatx4;

#define Bsz 2
#define Lseq 2048
#define Dmod 512
#define NHn 8
#define NLn 4
#define DMn 2048
#define Vn 32000
#define HDn 64
#define Mrows 4096  // B*L

typedef __attribute__((address_space(1))) const void cg_void;
typedef __attribute__((address_space(3))) void lds_void;

// ------------- transpose+cast: src_f32[R][C] -> dst_bf16[C][R] -------------
__global__ void transpose_kernel(const float* __restrict__ src, bf16* __restrict__ dst,
                                 int R, int C) {
    __shared__ float tile[32][33];
    int c0 = blockIdx.x * 32, r0 = blockIdx.y * 32;
    int tx = threadIdx.x, ty = threadIdx.y;  // block (32,8)
    #pragma unroll
    for (int i = 0; i < 32; i += 8)
        tile[ty + i][tx] = src[(long)(r0 + ty + i) * C + (c0 + tx)];
    __syncthreads();
    #pragma unroll
    for (int i = 0; i < 32; i += 8)
        dst[(long)(c0 + ty + i) * R + (r0 + tx)] = (bf16)tile[tx][ty + i];
}

// ---------------- embedding: h = tok_emb[x] + pos_emb (all f32) ----------------
__global__ __launch_bounds__(256) void embed_kernel(const int* __restrict__ x,
                                                    const float* __restrict__ tok,
                                                    const float* __restrict__ pos,
                                                    float* __restrict__ h) {
    int row = blockIdx.x;            // b*L + l
    int l = row & (Lseq - 1);
    int t = x[row];
    int d = threadIdx.x;
    #pragma unroll
    for (int i = 0; i < Dmod; i += 256) {
        int c = d + i;
        h[(long)row * Dmod + c] = tok[(long)t * Dmod + c] + pos[(long)l * Dmod + c];
    }
}

// ---------------- layernorm: out_bf16 = LN(h_f32)*g + b (g,b f32) ----------------
__global__ __launch_bounds__(256) void ln_kernel(const float* __restrict__ h,
                                                 const float* __restrict__ g,
                                                 const float* __restrict__ b,
                                                 bf16* __restrict__ out) {
    int wave = threadIdx.x >> 6, lane = threadIdx.x & 63;
    int row = blockIdx.x * 4 + wave;
    const float* hr = h + (long)row * Dmod;
    float v[8];
    float s = 0.f;
    #pragma unroll
    for (int i = 0; i < 8; i++) { v[i] = hr[i * 64 + lane]; s += v[i]; }
    #pragma unroll
    for (int o = 32; o > 0; o >>= 1) s += __shfl_xor(s, o, 64);
    float mu = s * (1.0f / Dmod);
    float sq = 0.f;
    #pragma unroll
    for (int i = 0; i < 8; i++) { float d0 = v[i] - mu; sq += d0 * d0; }
    #pragma unroll
    for (int o = 32; o > 0; o >>= 1) sq += __shfl_xor(sq, o, 64);
    float rstd = rsqrtf(sq * (1.0f / Dmod) + 1e-5f);
    #pragma unroll
    for (int i = 0; i < 8; i++) {
        int c = i * 64 + lane;
        out[(long)row * Dmod + c] = (bf16)((v[i] - mu) * rstd * g[c] + b[c]);
    }
}

// ---------------- GEMM: C[M,N] = A[M,K] @ B[K,N] (+bias f32), B given as BT[N,K]
// m97-style staging: global_load_lds width=16, linear LDS [rows][32] (no pad).
// Tile BM x 128, BK=32, 4 waves. BM=128: wave=64x64 (acc 4x4). BM=64: wave=32x64
// (acc 2x4) — doubles grid for small-N GEMMs.
// MODE 0: store bf16; MODE 1: gelu(exact)->bf16; MODE 2: h_f32 += C; MODE 3: f32
// MODE 4: qkv special — cols [0,1024) -> outb (Q,K); cols [1024,1536) (=V) -> vtb
//         transposed per head: vtb[(b*8+h)*64 + d][k]  (k contiguous, stride Lseq)
template <int MODE, int BM>
__global__ __launch_bounds__(256) void gemm_kernel(const bf16* __restrict__ A,
                                                   const bf16* __restrict__ BT,
                                                   const float* __restrict__ bias,
                                                   float* __restrict__ h,
                                                   bf16* __restrict__ outb,
                                                   float* __restrict__ outf,
                                                   bf16* __restrict__ vtb,
                                                   int N, int K) {
    constexpr int MT = (BM == 128) ? 4 : 2;   // 16-row m-frags per wave
    __shared__ __align__(16) short As[BM * 32];
    __shared__ __align__(16) short Bs[128 * 32];
    const int tid = threadIdx.x;
    const int wave = tid >> 6, lane = tid & 63;
    const int bm = blockIdx.y, bn = blockIdx.x;
    const int wm = (wave >> 1) * (MT * 16), wn = (wave & 1) * 64;
    const int quad = lane >> 4, l16 = lane & 15;

    floatx4 acc[MT][4] = {};

    // staging geometry: lane's 16B goes to ldsbase + lane*16; arrange global src
    // so that wave w covers rows [w*16, w*16+16), chunk (lane&3)*8 bf16
    const int srow = wave * 16 + (lane >> 2);   // 0..63
    const int scol = (lane & 3) * 8;
    const bf16* gA0 = A + (long)(bm * BM + srow) * K + scol;
    const bf16* gA1 = A + (long)(bm * BM + 64 + srow) * K + scol;  // BM==128 only
    const bf16* gB0 = BT + (long)(bn * 128 + srow) * K + scol;
    const bf16* gB1 = BT + (long)(bn * 128 + 64 + srow) * K + scol;
    short* lA0 = As + (wave * 16) * 32;          // wave-uniform LDS bases
    short* lA1 = As + (64 + wave * 16) * 32;
    short* lB0 = Bs + (wave * 16) * 32;
    short* lB1 = Bs + (64 + wave * 16) * 32;

    for (int k0 = 0; k0 < K; k0 += 32) {
        __syncthreads();
        __builtin_amdgcn_global_load_lds((cg_void*)(gA0 + k0), (lds_void*)lA0, 16, 0, 0);
        if constexpr (BM == 128)
            __builtin_amdgcn_global_load_lds((cg_void*)(gA1 + k0), (lds_void*)lA1, 16, 0, 0);
        __builtin_amdgcn_global_load_lds((cg_void*)(gB0 + k0), (lds_void*)lB0, 16, 0, 0);
        __builtin_amdgcn_global_load_lds((cg_void*)(gB1 + k0), (lds_void*)lB1, 16, 0, 0);
        __syncthreads();   // compiler drains vmcnt(0) before the barrier

        short8 af[MT], bfr[4];
        #pragma unroll
        for (int t = 0; t < MT; t++)
            af[t] = *(const short8*)(As + (wm + t * 16 + l16) * 32 + quad * 8);
        #pragma unroll
        for (int t = 0; t < 4; t++)
            bfr[t] = *(const short8*)(Bs + (wn + t * 16 + l16) * 32 + quad * 8);
        #pragma unroll
        for (int mt = 0; mt < MT; mt++)
            #pragma unroll
            for (int nt = 0; nt < 4; nt++)
                acc[mt][nt] = __builtin_amdgcn_mfma_f32_16x16x32_bf16(af[mt], bfr[nt], acc[mt][nt], 0, 0, 0);
    }

    #pragma unroll
    for (int mt = 0; mt < MT; mt++) {
        int row = bm * BM + wm + mt * 16 + quad * 4;
        #pragma unroll
        for (int nt = 0; nt < 4; nt++) {
            int col = bn * 128 + wn + nt * 16 + l16;
            float bv = bias ? bias[col] : 0.0f;
            #pragma unroll
            for (int r = 0; r < 4; r++) {
                float c = acc[mt][nt][r] + bv;
                long off = (long)(row + r) * N + col;
                if (MODE == 0) {
                    outb[off] = (bf16)c;
                } else if (MODE == 1) {
                    float gl = 0.5f * c * (1.0f + erff(c * 0.70710678118f));
                    outb[off] = (bf16)gl;
                } else if (MODE == 2) {
                    h[off] += c;
                } else if (MODE == 3) {
                    outf[off] = c;
                } else {  // MODE 4: QKV with V transposed per head
                    if (col < 2 * Dmod) {
                        outb[off] = (bf16)c;
                    } else {
                        int d  = col - 2 * Dmod;        // 0..511 (= h*64 + dd)
                        int b_ = (row + r) >> 11;       // batch
                        int k  = (row + r) & (Lseq - 1);
                        vtb[(long)(b_ * 512 + d) * Lseq + k] = (bf16)c;
                    }
                }
            }
        }
    }
}

// ---------------- MFMA flash attention ----------------
// One wave = one 16-query tile of one (b,h). 64-key inner step (4 S-tiles) so
// the serial softmax chains (max/alpha/rescale/lsum) amortize over 2x keys.
// S^T = mfma(K_frag, Q_frag): C col = query = lane&15, row = key = quad*4+r.
// defer-max: skip rescale when no query saw a new max (alpha==1 exactly).
__global__ __launch_bounds__(256) void attn_mfma_kernel(const bf16* __restrict__ qkv,
                                                        const bf16* __restrict__ vt,
                                                        bf16* __restrict__ o_out) {
    const int tid  = threadIdx.x;
    const int wave = tid >> 6, lane = tid & 63;
    const int l16  = lane & 15, quad = lane >> 4;
    const int bh = blockIdx.x & 15;            // 4 waves of a block share (b,h)
    const int jg = blockIdx.x >> 4;            // 0..31
    const int qb = 127 - (jg * 4 + wave);      // heavy q-tiles dispatched first
    const int b = bh >> 3, h = bh & 7;
    const int q0 = qb * 16;

    const bf16* qbase = qkv + (long)(b * Lseq + q0 + l16) * 1536 + h * 64;
    const bf16* kbase = qkv + (long)b * Lseq * 1536 + Dmod + h * 64;
    const bf16* vbase = vt + (long)(bh * 64 + l16) * Lseq;

    const short8 qf0 = *(const short8*)(qbase + quad * 8);        // Q[q=l16][d 0..31]
    const short8 qf1 = *(const short8*)(qbase + 32 + quad * 8);   // Q[q=l16][d 32..63]

    floatx4 o_acc[4] = {};        // o_acc[nt][r] = O[q=quad*4+r][d=nt*16+l16]
    float m = -1e30f, lsum = 0.f;
    const int qg = q0 + l16;      // this lane's query (softmax domain)
    const float scale = 0.125f;   // 1/sqrt(64)

    for (int k0 = 0; k0 < q0 + 16; k0 += 64) {
        // ---- S^T for keys [k0, k0+64) : four 16x16 tiles ----
        float t[4][4];
        #pragma unroll
        for (int tt = 0; tt < 4; tt++) {
            const bf16* krow = kbase + (long)(k0 + tt * 16 + l16) * 1536;
            floatx4 s = {};
            short8 kf0 = *(const short8*)(krow + quad * 8);
            short8 kf1 = *(const short8*)(krow + 32 + quad * 8);
            s = __builtin_amdgcn_mfma_f32_16x16x32_bf16(kf0, qf0, s, 0, 0, 0);
            s = __builtin_amdgcn_mfma_f32_16x16x32_bf16(kf1, qf1, s, 0, 0, 0);
            #pragma unroll
            for (int r = 0; r < 4; r++) {
                int ka = k0 + tt * 16 + quad * 4 + r;
                t[tt][r] = (ka <= qg) ? s[r] * scale : -1e30f;
            }
        }

        // ---- online softmax per query (= l16 column) ----
        float pm = t[0][0];
        #pragma unroll
        for (int tt = 0; tt < 4; tt++)
            #pragma unroll
            for (int r = 0; r < 4; r++) pm = fmaxf(pm, t[tt][r]);
        pm = fmaxf(pm, __shfl_xor(pm, 16, 64));
        pm = fmaxf(pm, __shfl_xor(pm, 32, 64));

        float mnew, alpha;
        bool noresc = __all(pm <= m);
        if (noresc) { mnew = m; alpha = 1.0f; }
        else        { mnew = fmaxf(m, pm); alpha = __expf(m - mnew); }

        float p[4][4], es = 0.f;
        #pragma unroll
        for (int tt = 0; tt < 4; tt++)
            #pragma unroll
            for (int r = 0; r < 4; r++) {
                // quantize P to bf16 BEFORE summing: denominator matches PV numerator
                bf16 pq = (bf16)__expf(t[tt][r] - mnew);
                p[tt][r] = (float)pq;
                es += p[tt][r];
            }
        es += __shfl_xor(es, 16, 64);
        es += __shfl_xor(es, 32, 64);
        lsum = lsum * alpha + es;
        m = mnew;

        // ---- rescale O only when some query got a new max ----
        if (!noresc) {
            #pragma unroll
            for (int r = 0; r < 4; r++) {
                float aq = __shfl(alpha, quad * 4 + r, 64);
                o_acc[0][r] *= aq; o_acc[1][r] *= aq;
                o_acc[2][r] *= aq; o_acc[3][r] *= aq;
            }
        }

        // ---- P^T -> P A-fragment + PV, per 32-key group g ----
        // lane needs P[q=l16][k0 + g*32 + quad*8 + j], j=0..7
        const int sl0 = l16 | (((quad * 2) & 3) << 4);
        const int sl1 = l16 | (((quad * 2 + 1) & 3) << 4);
        #pragma unroll
        for (int g = 0; g < 2; g++) {
            short8 pf;
            #pragma unroll
            for (int r = 0; r < 4; r++) {
                float a0 = __shfl(p[2 * g][r], sl0, 64);
                float a1 = __shfl(p[2 * g + 1][r], sl0, 64);
                float va = (quad < 2) ? a0 : a1;     // tile = quad>>1 within group
                float b0 = __shfl(p[2 * g][r], sl1, 64);
                float b1 = __shfl(p[2 * g + 1][r], sl1, 64);
                float vb = (quad < 2) ? b0 : b1;
                bf16 ta = (bf16)va;                  // exact: already bf16-quantized
                bf16 tb = (bf16)vb;
                pf[r]     = __builtin_bit_cast(short, ta);
                pf[4 + r] = __builtin_bit_cast(short, tb);
            }
            const bf16* vrow = vbase + k0 + g * 32 + quad * 8;
            #pragma unroll
            for (int nt = 0; nt < 4; nt++) {
                short8 vf = *(const short8*)(vrow + (long)nt * 16 * Lseq);
                o_acc[nt] = __builtin_amdgcn_mfma_f32_16x16x32_bf16(pf, vf, o_acc[nt], 0, 0, 0);
            }
        }
    }

    // ---- epilogue: normalize rows by their lsum and store ----
    #pragma unroll
    for (int r = 0; r < 4; r++) {
        float lq  = __shfl(lsum, quad * 4 + r, 64);
        float inv = 1.0f / lq;
        int row = b * Lseq + q0 + quad * 4 + r;
        #pragma unroll
        for (int nt = 0; nt < 4; nt++)
            o_out[(long)row * Dmod + h * 64 + nt * 16 + l16] = (bf16)(o_acc[nt][r] * inv);
    }
}

// ---------------- host launch ----------------
extern "C" void kernel_launch(void* const* d_in, const int* in_sizes, int n_in,
                              void* d_out, int out_size, void* d_ws, size_t ws_size,
                              hipStream_t stream) {
    const int*   x      = (const int*)d_in[0];
    const float* tok    = (const float*)d_in[1];
    const float* pos    = (const float*)d_in[2];
    const float* ln1_g  = (const float*)d_in[3];
    const float* ln1_b  = (const float*)d_in[4];
    const float* qkv_w  = (const float*)d_in[5];
    const float* qkv_b  = (const float*)d_in[6];
    const float* out_w  = (const float*)d_in[7];
    const float* out_b  = (const float*)d_in[8];
    const float* ln2_g  = (const float*)d_in[9];
    const float* ln2_b  = (const float*)d_in[10];
    const float* w1     = (const float*)d_in[11];
    const float* b1     = (const float*)d_in[12];
    const float* w2     = (const float*)d_in[13];
    const float* b2     = (const float*)d_in[14];
    const float* lnf_g  = (const float*)d_in[15];
    const float* lnf_b  = (const float*)d_in[16];
    const float* head_w = (const float*)d_in[17];
    float* out = (float*)d_out;

    char* w = (char*)d_ws;
    float* h      = (float*)(w + 0);              // 4096x512 f32    =  8,388,608
    bf16*  lnbuf  = (bf16*)(w + 8388608);         // 4096x512 bf16   =  4,194,304
    bf16*  qkvbuf = (bf16*)(w + 12582912);        // 4096x1536 bf16  = 12,582,912
    bf16*  attn_o = (bf16*)(w + 25165824);        // 4096x512 bf16   =  4,194,304
    bf16*  mlpbuf = (bf16*)(w + 29360128);        // 4096x2048 bf16  = 16,777,216
    bf16*  vT     = mlpbuf;                       // VT[1024][2048] bf16 = 4 MB,
                                                  // aliases mlpbuf (free during attn)
    bf16*  qkvT   = (bf16*)(w + 46137344);        // 4x1536x512      =  6,291,456
    bf16*  outT   = (bf16*)(w + 52428800);        // 4x512x512       =  2,097,152
    bf16*  w1T    = (bf16*)(w + 54525952);        // 4x2048x512      =  8,388,608
    bf16*  w2T    = (bf16*)(w + 62914560);        // 4x512x2048      =  8,388,608
    bf16*  headT  = (bf16*)(w + 71303168);        // 32000x512       = 32,768,000
    // total ws need: 104,071,168 bytes

    dim3 tb(32, 8);
    for (int l = 0; l < NLn; l++) {
        transpose_kernel<<<dim3(3 * Dmod / 32, Dmod / 32), tb, 0, stream>>>(
            qkv_w + (long)l * Dmod * 3 * Dmod, qkvT + (long)l * 3 * Dmod * Dmod, Dmod, 3 * Dmod);
        transpose_kernel<<<dim3(Dmod / 32, Dmod / 32), tb, 0, stream>>>(
            out_w + (long)l * Dmod * Dmod, outT + (long)l * Dmod * Dmod, Dmod, Dmod);
        transpose_kernel<<<dim3(DMn / 32, Dmod / 32), tb, 0, stream>>>(
            w1 + (long)l * Dmod * DMn, w1T + (long)l * DMn * Dmod, Dmod, DMn);
        transpose_kernel<<<dim3(Dmod / 32, DMn / 32), tb, 0, stream>>>(
            w2 + (long)l * DMn * Dmod, w2T + (long)l * Dmod * DMn, DMn, Dmod);
    }
    transpose_kernel<<<dim3(Vn / 32, Dmod / 32), tb, 0, stream>>>(head_w, headT, Dmod, Vn);

    embed_kernel<<<Mrows, 256, 0, stream>>>(x, tok, pos, h);

    for (int l = 0; l < NLn; l++) {
        ln_kernel<<<Mrows / 4, 256, 0, stream>>>(h, ln1_g + l * Dmod, ln1_b + l * Dmod, lnbuf);
        gemm_kernel<4, 64><<<dim3(3 * Dmod / 128, Mrows / 64), 256, 0, stream>>>(
            lnbuf, qkvT + (long)l * 3 * Dmod * Dmod, qkv_b + l * 3 * Dmod, nullptr, qkvbuf,
            nullptr, vT, 3 * Dmod, Dmod);
        attn_mfma_kernel<<<512, 256, 0, stream>>>(qkvbuf, vT, attn_o);
        gemm_kernel<2, 64><<<dim3(Dmod / 128, Mrows / 64), 256, 0, stream>>>(
            attn_o, outT + (long)l * Dmod * Dmod, out_b + l * Dmod, h, nullptr, nullptr,
            nullptr, Dmod, Dmod);
        ln_kernel<<<Mrows / 4, 256, 0, stream>>>(h, ln2_g + l * Dmod, ln2_b + l * Dmod, lnbuf);
        gemm_kernel<1, 128><<<dim3(DMn / 128, Mrows / 128), 256, 0, stream>>>(
            lnbuf, w1T + (long)l * DMn * Dmod, b1 + l * DMn, nullptr, mlpbuf, nullptr,
            nullptr, DMn, Dmod);
        gemm_kernel<2, 64><<<dim3(Dmod / 128, Mrows / 64), 256, 0, stream>>>(
            mlpbuf, w2T + (long)l * Dmod * DMn, b2 + l * Dmod, h, nullptr, nullptr,
            nullptr, Dmod, DMn);
    }
    ln_kernel<<<Mrows / 4, 256, 0, stream>>>(h, lnf_g, lnf_b, lnbuf);
    gemm_kernel<3, 128><<<dim3(Vn / 128, Mrows / 128), 256, 0, stream>>>(
        lnbuf, headT, nullptr, nullptr, nullptr, out, nullptr, Vn, Dmod);
}